// Round 2
// baseline (957.613 us; speedup 1.0000x reference)
//
#include <hip/hip_runtime.h>

// ---------- problem constants ----------
#define T_TOK 4096
#define NROWS_MAX 10240  // 8192 routed rows + per-expert 256-alignment padding
#define MAX_TILES 40     // sum ceil(c_e/256) <= 32 + 7 = 39

typedef float  fv4  __attribute__((ext_vector_type(4)));
typedef __bf16 bv4  __attribute__((ext_vector_type(4)));
typedef __bf16 bv8  __attribute__((ext_vector_type(8)));

// ---------- workspace layout (bytes) ----------
#define CTRL_OFF     0
#define ROWTOK_OFF   4096         // int[10240]
#define ROWGATE_OFF  45056        // float[10240]
#define TOPIDX_OFF   86016        // int[8192]
#define TOPVAL_OFF   118784       // float[8192]
#define G_OFF        151552       // float[4096*256]
#define XB_OFF       4345856      // bf16[4096*2048]
#define W1T_OFF      21123072     // bf16[8*2048*2048]  ([E][H][D] = B^T)
#define W2T_OFF      88231936     // bf16[8*2048*2048]  ([E][D][H] = B^T)
#define HBUF_OFF     155340800    // bf16[10240*2048]
// total ~197 MB

struct Ctrl {
    int   counts[8];
    float psum[8];
    float entsum;
    int   ntiles;
    int   off[8];
    int   tile_e[MAX_TILES];
    int   tile_r0[MAX_TILES];
};

__device__ __forceinline__ float gelu_f(float x) {
    float x3 = x * x * x;
    return 0.5f * x * (1.0f + tanhf(0.7978845608028654f * (x + 0.044715f * x3)));
}

__device__ __forceinline__ void g2l16(const void* gptr, void* lptr) {
    __builtin_amdgcn_global_load_lds(
        (const __attribute__((address_space(1))) void*)gptr,
        (__attribute__((address_space(3))) void*)lptr, 16, 0, 0);
}

// ---------- K0a: w1/w2 fp32 -> bf16, transposed per expert ----------
__global__ __launch_bounds__(256) void transpose_cvt(
    const float* __restrict__ w1, const float* __restrict__ w2,
    __bf16* __restrict__ w1t, __bf16* __restrict__ w2t)
{
    int b    = blockIdx.x;
    int mat  = b >> 10;
    int tile = b & 1023;
    int trow = tile >> 5, tcol = tile & 31;
    const float* src = (mat < 8) ? (w1 + (size_t)mat * 4194304)
                                 : (w2 + (size_t)(mat - 8) * 4194304);
    __bf16* dst = (mat < 8) ? (w1t + (size_t)mat * 4194304)
                            : (w2t + (size_t)(mat - 8) * 4194304);
    __shared__ float tileS[64][65];
    int tid = threadIdx.x;
    int c = tid & 63, r4 = tid >> 6;
#pragma unroll
    for (int u = 0; u < 16; u++) {
        int rr = u * 4 + r4;
        tileS[rr][c] = src[(size_t)(trow * 64 + rr) * 2048 + tcol * 64 + c];
    }
    __syncthreads();
    int c2 = (tid & 31) * 2, r8 = tid >> 5;
#pragma unroll
    for (int u = 0; u < 8; u++) {
        int rr = u * 8 + r8;
        __bf16 v0 = (__bf16)tileS[c2][rr];
        __bf16 v1 = (__bf16)tileS[c2 + 1][rr];
        size_t o = (size_t)(tcol * 64 + rr) * 2048 + trow * 64 + c2;
        dst[o]     = v0;
        dst[o + 1] = v1;
    }
}

// ---------- K0b: x fp32 -> bf16 ----------
__global__ __launch_bounds__(256) void cvt_x_kernel(const float* __restrict__ x,
                                                    __bf16* __restrict__ xb)
{
    size_t idx = ((size_t)blockIdx.x * 256 + threadIdx.x) * 4;
    fv4 v = *(const fv4*)(x + idx);
    bv4 o;
#pragma unroll
    for (int u = 0; u < 4; u++) o[u] = (__bf16)v[u];
    *(bv4*)(xb + idx) = o;
}

// ---------- K1: g = gelu(x @ wg1), fp32 (top-k precision-critical) ----------
__global__ __launch_bounds__(256) void gating_gemm(const float* __restrict__ x,
                                                   const float* __restrict__ wg1,
                                                   float* __restrict__ g)
{
    __shared__ float As[16][68];
    __shared__ float Bs[16][68];
    int tid = threadIdx.x;
    int tx = tid & 15, ty = tid >> 4;
    int mb = blockIdx.x, nb = blockIdx.y;
    float acc[4][4];
#pragma unroll
    for (int u = 0; u < 4; u++)
#pragma unroll
        for (int v = 0; v < 4; v++) acc[u][v] = 0.f;

    int r  = tid >> 2, kq = tid & 3;
    int kb = tid >> 4, n4 = (tid & 15) * 4;
    const float* gx = x + (size_t)(mb * 64 + r) * 2048 + kq * 4;
    const float* gw = wg1 + nb * 64 + n4;

    for (int k0 = 0; k0 < 2048; k0 += 16) {
        fv4 av = *(const fv4*)(gx + k0);
        fv4 bv = *(const fv4*)(gw + (size_t)(k0 + kb) * 256);
        __syncthreads();
#pragma unroll
        for (int u = 0; u < 4; u++) As[kq * 4 + u][r] = av[u];
        *(fv4*)&Bs[kb][n4] = bv;
        __syncthreads();
#pragma unroll
        for (int k = 0; k < 16; k++) {
            fv4 a = *(const fv4*)&As[k][ty * 4];
            fv4 b = *(const fv4*)&Bs[k][tx * 4];
#pragma unroll
            for (int u = 0; u < 4; u++)
#pragma unroll
                for (int v = 0; v < 4; v++) acc[u][v] += a[u] * b[v];
        }
    }
#pragma unroll
    for (int u = 0; u < 4; u++) {
        int row = mb * 64 + ty * 4 + u;
#pragma unroll
        for (int v = 0; v < 4; v++)
            g[(size_t)row * 256 + nb * 64 + tx * 4 + v] = gelu_f(acc[u][v]);
    }
}

// ---------- K2: logits = g @ wg2, softmax, top-2, loss partials ----------
__global__ __launch_bounds__(256) void gate_kernel(
    const float* __restrict__ g, const float* __restrict__ wg2,
    Ctrl* __restrict__ ctrl, int* __restrict__ topidx, float* __restrict__ topval)
{
    __shared__ float wg2s[256 * 9];
    __shared__ float psum_s[8];
    __shared__ float ent_s;
    __shared__ int   cnt_s[8];
    int tid = threadIdx.x;
    for (int i = tid; i < 2048; i += 256) {
        int k = i >> 3, e = i & 7;
        wg2s[k * 9 + e] = wg2[i];
    }
    if (tid < 8) { psum_s[tid] = 0.f; cnt_s[tid] = 0; }
    if (tid == 8) ent_s = 0.f;
    __syncthreads();

    int lane = tid & 63, wv = tid >> 6;
    int t = blockIdx.x * 4 + wv;
    fv4 g4 = *(const fv4*)&g[(size_t)t * 256 + lane * 4];
    float part[8];
#pragma unroll
    for (int e = 0; e < 8; e++) part[e] = 0.f;
#pragma unroll
    for (int u = 0; u < 4; u++) {
        int k = lane * 4 + u;
        float gv = g4[u];
#pragma unroll
        for (int e = 0; e < 8; e++) part[e] += gv * wg2s[k * 9 + e];
    }
#pragma unroll
    for (int e = 0; e < 8; e++)
        for (int off = 32; off; off >>= 1) part[e] += __shfl_xor(part[e], off);

    if (lane == 0) {
        float mx = part[0];
#pragma unroll
        for (int e = 1; e < 8; e++) mx = fmaxf(mx, part[e]);
        float p[8], Z = 0.f;
#pragma unroll
        for (int e = 0; e < 8; e++) { p[e] = expf(part[e] - mx); Z += p[e]; }
        float rz = 1.f / Z;
#pragma unroll
        for (int e = 0; e < 8; e++) p[e] *= rz;
        int i0 = 0;
#pragma unroll
        for (int e = 1; e < 8; e++) if (part[e] > part[i0]) i0 = e;
        int i1 = (i0 == 0) ? 1 : 0;
#pragma unroll
        for (int e = 0; e < 8; e++)
            if (e != i0 && part[e] > part[i1]) i1 = e;
        topidx[2 * t]     = i0;
        topidx[2 * t + 1] = i1;
        topval[2 * t]     = p[i0];
        topval[2 * t + 1] = p[i1];
        float ent = 0.f;
#pragma unroll
        for (int e = 0; e < 8; e++) ent += p[e] * logf(p[e] + 1e-9f);
#pragma unroll
        for (int e = 0; e < 8; e++) atomicAdd(&psum_s[e], p[e]);
        atomicAdd(&ent_s, ent);
        atomicAdd(&cnt_s[i0], 1);
        atomicAdd(&cnt_s[i1], 1);
    }
    __syncthreads();
    if (tid < 8)                    atomicAdd(&ctrl->psum[tid], psum_s[tid]);
    else if (tid == 8)              atomicAdd(&ctrl->entsum, ent_s);
    else if (tid >= 16 && tid < 24) atomicAdd(&ctrl->counts[tid - 16], cnt_s[tid - 16]);
}

// ---------- K4: offsets + tile map (256-granular) + scatter ----------
__global__ __launch_bounds__(256) void route_kernel(
    Ctrl* __restrict__ ctrl, const int* __restrict__ topidx,
    const float* __restrict__ topval, int* __restrict__ rowtok,
    float* __restrict__ rowgate)
{
    __shared__ int cur[8];
    __shared__ int offs_s[8];
    int tid = threadIdx.x;
    if (tid == 0) {
        int off = 0, nt = 0;
        for (int e = 0; e < 8; e++) {
            offs_s[e]    = off;
            ctrl->off[e] = off;
            int c = ctrl->counts[e];
            for (int m = 0; m < c; m += 256) {
                ctrl->tile_e[nt]  = e;
                ctrl->tile_r0[nt] = off + m;
                nt++;
            }
            off += ((c + 255) >> 8) << 8;
        }
        ctrl->ntiles = nt;
    }
    if (tid < 8) cur[tid] = 0;
    __syncthreads();
    for (int t = tid; t < T_TOK; t += 256) {
#pragma unroll
        for (int k = 0; k < 2; k++) {
            int e = topidx[2 * t + k];
            int p = atomicAdd(&cur[e], 1);
            int row = offs_s[e] + p;
            rowtok[row]  = t;
            rowgate[row] = topval[2 * t + k];
        }
    }
}

// ---------- grouped MFMA GEMM: 256x256 tile, BK=32, XCD swizzle, LDS XOR swizzle ----
// 512 threads = 8 waves in 4x2 grid; wave computes 64x128 (acc 4x8).
template <bool IS_FFN1>
__global__ __launch_bounds__(512, 2) void gemm_grouped(
    const __bf16* __restrict__ A,
    const __bf16* __restrict__ Bt,   // [E][N=2048][K=2048] (B^T)
    const Ctrl* __restrict__ ctrl,
    const int* __restrict__ rowtok,
    const float* __restrict__ rowgate,
    __bf16* __restrict__ hbuf,
    float* __restrict__ y)
{
    // XCD-aware swizzle: XCD k owns tiles [5k,5k+5) x all 8 nb
    int lb   = blockIdx.x;               // 0..319
    int tile = (lb & 7) * 5 + (lb >> 6);
    int nb   = (lb >> 3) & 7;
    if (tile >= ctrl->ntiles) return;
    int e  = ctrl->tile_e[tile];
    int r0 = ctrl->tile_r0[tile];
    const int K = 2048;

    __shared__ __bf16 As[256 * 32];
    __shared__ __bf16 Bs[256 * 32];

    int tid  = threadIdx.x;
    int lane = tid & 63, w = tid >> 6;
    int wr = w >> 1, wc = w & 1;

    // staging: wave w owns chunks {2w,2w+1} of As and Bs (16 rows x 64B each)
    int c0 = 2 * w, c1 = c0 + 1;
    int sub = lane >> 2;
    int kcg = (lane & 3) ^ ((lane >> 3) & 3);   // XOR bank swizzle

    int rA0 = c0 * 16 + sub, rA1 = c1 * 16 + sub;
    size_t ga0, ga1;
    if constexpr (IS_FFN1) {
        ga0 = (size_t)rowtok[r0 + rA0] * K;
        ga1 = (size_t)rowtok[r0 + rA1] * K;
    } else {
        ga0 = (size_t)(r0 + rA0) * K;
        ga1 = (size_t)(r0 + rA1) * K;
    }
    const __bf16* gA0 = A + ga0 + kcg * 8;
    const __bf16* gA1 = A + ga1 + kcg * 8;
    const __bf16* gB0 = Bt + ((size_t)e * 2048 + nb * 256 + c0 * 16 + sub) * K + kcg * 8;
    const __bf16* gB1 = Bt + ((size_t)e * 2048 + nb * 256 + c1 * 16 + sub) * K + kcg * 8;
    __bf16* lA0 = &As[c0 * 512];
    __bf16* lA1 = &As[c1 * 512];
    __bf16* lB0 = &Bs[c0 * 512];
    __bf16* lB1 = &Bs[c1 * 512];

    fv4 acc[4][8];
#pragma unroll
    for (int i = 0; i < 4; i++)
#pragma unroll
        for (int j = 0; j < 8; j++) acc[i][j] = (fv4)0.0f;

    // fragment read offset: row r, kc=lane>>4 stored at slot kc^((r>>1)&3)
    int frow = (lane & 15) * 32 + (((lane >> 4) ^ ((lane >> 1) & 3)) * 8);

    for (int k0 = 0; k0 < K; k0 += 32) {
        __syncthreads();
        g2l16(gA0, lA0);
        g2l16(gA1, lA1);
        g2l16(gB0, lB0);
        g2l16(gB1, lB1);
        gA0 += 32; gA1 += 32; gB0 += 32; gB1 += 32;
        __syncthreads();
        bv8 aF[4], bF[8];
#pragma unroll
        for (int i = 0; i < 4; i++) aF[i] = *(const bv8*)&As[(wr * 64 + i * 16) * 32 + frow];
#pragma unroll
        for (int j = 0; j < 8; j++) bF[j] = *(const bv8*)&Bs[(wc * 128 + j * 16) * 32 + frow];
#pragma unroll
        for (int i = 0; i < 4; i++)
#pragma unroll
            for (int j = 0; j < 8; j++)
                acc[i][j] = __builtin_amdgcn_mfma_f32_16x16x32_bf16(aF[i], bF[j], acc[i][j], 0, 0, 0);
    }

    // epilogue: C/D layout col=lane&15, row=(lane>>4)*4+reg
    int colb = nb * 256 + wc * 128 + (lane & 15);
    int rb   = r0 + wr * 64 + (lane >> 4) * 4;
#pragma unroll
    for (int i = 0; i < 4; i++) {
#pragma unroll
        for (int rr = 0; rr < 4; rr++) {
            int rg = rb + i * 16 + rr;
            if constexpr (IS_FFN1) {
                float gate = rowgate[rg];
                size_t ho = (size_t)rg * 2048;
#pragma unroll
                for (int j = 0; j < 8; j++)
                    hbuf[ho + colb + j * 16] = (__bf16)(gelu_f(acc[i][j][rr]) * gate);
            } else {
                size_t yo = (size_t)rowtok[rg] * 2048;
#pragma unroll
                for (int j = 0; j < 8; j++)
                    atomicAdd(&y[yo + colb + j * 16], acc[i][j][rr]);
            }
        }
    }
}

// ---------- K5: final loss scalar ----------
__global__ __launch_bounds__(64) void loss_kernel(const Ctrl* __restrict__ ctrl,
                                                  float* __restrict__ out)
{
    if (threadIdx.x == 0) {
        float a = 0.f;
#pragma unroll
        for (int e = 0; e < 8; e++) {
            float pm = ctrl->psum[e] * (1.0f / 4096.0f);
            a += pm * logf(pm + 1e-9f);
        }
        out[0] = a - ctrl->entsum * (1.0f / 4096.0f);
    }
}

extern "C" void kernel_launch(void* const* d_in, const int* in_sizes, int n_in,
                              void* d_out, int out_size, void* d_ws, size_t ws_size,
                              hipStream_t stream)
{
    const float* x   = (const float*)d_in[0];
    const float* wg1 = (const float*)d_in[1];
    const float* wg2 = (const float*)d_in[2];
    const float* w1  = (const float*)d_in[3];
    const float* w2  = (const float*)d_in[4];
    float* out = (float*)d_out;

    char* ws = (char*)d_ws;
    Ctrl*   ctrl    = (Ctrl*)(ws + CTRL_OFF);
    int*    rowtok  = (int*)(ws + ROWTOK_OFF);
    float*  rowgate = (float*)(ws + ROWGATE_OFF);
    int*    topidx  = (int*)(ws + TOPIDX_OFF);
    float*  topval  = (float*)(ws + TOPVAL_OFF);
    float*  g       = (float*)(ws + G_OFF);
    __bf16* xb      = (__bf16*)(ws + XB_OFF);
    __bf16* w1t     = (__bf16*)(ws + W1T_OFF);
    __bf16* w2t     = (__bf16*)(ws + W2T_OFF);
    __bf16* hbuf    = (__bf16*)(ws + HBUF_OFF);

    hipMemsetAsync(ws + CTRL_OFF, 0, 4096, stream);
    hipMemsetAsync(ws + ROWTOK_OFF, 0, 81920, stream);   // rowtok + rowgate
    hipMemsetAsync(d_out, 0, (size_t)out_size * sizeof(float), stream);

    transpose_cvt<<<16384, 256, 0, stream>>>(w1, w2, w1t, w2t);
    cvt_x_kernel<<<8192, 256, 0, stream>>>(x, xb);
    gating_gemm<<<dim3(64, 4), 256, 0, stream>>>(x, wg1, g);
    gate_kernel<<<1024, 256, 0, stream>>>(g, wg2, ctrl, topidx, topval);
    route_kernel<<<1, 256, 0, stream>>>(ctrl, topidx, topval, rowtok, rowgate);
    gemm_grouped<true><<<320, 512, 0, stream>>>(xb, w1t, ctrl, rowtok, rowgate, hbuf, nullptr);
    gemm_grouped<false><<<320, 512, 0, stream>>>(hbuf, w2t, ctrl, rowtok, rowgate, nullptr, out);
    loss_kernel<<<1, 64, 0, stream>>>(ctrl, out + 8388608);
}

// Round 3
// 871.909 us; speedup vs baseline: 1.0983x; 1.0983x over previous
//
#include <hip/hip_runtime.h>

// ---------- problem constants ----------
#define T_TOK 4096
#define NROWS_MAX 10240  // 8192 routed rows + per-expert 256-alignment padding
#define MAX_TILES 40     // sum ceil(c_e/256) <= 32 + 7 = 39

typedef float  fv4  __attribute__((ext_vector_type(4)));
typedef __bf16 bv4  __attribute__((ext_vector_type(4)));
typedef __bf16 bv8  __attribute__((ext_vector_type(8)));

// ---------- workspace layout (bytes) ----------
#define CTRL_OFF     0
#define ROWTOK_OFF   4096         // int[10240]
#define ROWGATE_OFF  45056        // float[10240]
#define TOPIDX_OFF   86016        // int[8192]
#define TOPVAL_OFF   118784       // float[8192]
#define G_OFF        151552       // float[4096*256]
#define XB_OFF       4345856      // bf16[4096*2048]
#define W1T_OFF      21123072     // bf16[8*2048*2048]  ([E][H][D] = B^T)
#define W2T_OFF      88231936     // bf16[8*2048*2048]  ([E][D][H] = B^T)
#define HBUF_OFF     155340800    // bf16[10240*2048]
// total ~197 MB

struct Ctrl {
    int   counts[8];
    float psum[8];
    float entsum;
    int   ntiles;
    int   off[8];
    int   tile_e[MAX_TILES];
    int   tile_r0[MAX_TILES];
};

__device__ __forceinline__ float gelu_f(float x) {
    float x3 = x * x * x;
    return 0.5f * x * (1.0f + tanhf(0.7978845608028654f * (x + 0.044715f * x3)));
}

__device__ __forceinline__ void g2l16(const void* gptr, void* lptr) {
    __builtin_amdgcn_global_load_lds(
        (const __attribute__((address_space(1))) void*)gptr,
        (__attribute__((address_space(3))) void*)lptr, 16, 0, 0);
}

// ---------- K0a: w1/w2 fp32 -> bf16, transposed per expert ----------
__global__ __launch_bounds__(256) void transpose_cvt(
    const float* __restrict__ w1, const float* __restrict__ w2,
    __bf16* __restrict__ w1t, __bf16* __restrict__ w2t)
{
    int b    = blockIdx.x;
    int mat  = b >> 10;
    int tile = b & 1023;
    int trow = tile >> 5, tcol = tile & 31;
    const float* src = (mat < 8) ? (w1 + (size_t)mat * 4194304)
                                 : (w2 + (size_t)(mat - 8) * 4194304);
    __bf16* dst = (mat < 8) ? (w1t + (size_t)mat * 4194304)
                            : (w2t + (size_t)(mat - 8) * 4194304);
    __shared__ float tileS[64][65];
    int tid = threadIdx.x;
    int c = tid & 63, r4 = tid >> 6;
#pragma unroll
    for (int u = 0; u < 16; u++) {
        int rr = u * 4 + r4;
        tileS[rr][c] = src[(size_t)(trow * 64 + rr) * 2048 + tcol * 64 + c];
    }
    __syncthreads();
    int c2 = (tid & 31) * 2, r8 = tid >> 5;
#pragma unroll
    for (int u = 0; u < 8; u++) {
        int rr = u * 8 + r8;
        __bf16 v0 = (__bf16)tileS[c2][rr];
        __bf16 v1 = (__bf16)tileS[c2 + 1][rr];
        size_t o = (size_t)(tcol * 64 + rr) * 2048 + trow * 64 + c2;
        dst[o]     = v0;
        dst[o + 1] = v1;
    }
}

// ---------- K0b: x fp32 -> bf16 ----------
__global__ __launch_bounds__(256) void cvt_x_kernel(const float* __restrict__ x,
                                                    __bf16* __restrict__ xb)
{
    size_t idx = ((size_t)blockIdx.x * 256 + threadIdx.x) * 4;
    fv4 v = *(const fv4*)(x + idx);
    bv4 o;
#pragma unroll
    for (int u = 0; u < 4; u++) o[u] = (__bf16)v[u];
    *(bv4*)(xb + idx) = o;
}

// ---------- K1: g = gelu(x @ wg1), fp32 (top-k precision-critical) ----------
__global__ __launch_bounds__(256) void gating_gemm(const float* __restrict__ x,
                                                   const float* __restrict__ wg1,
                                                   float* __restrict__ g)
{
    __shared__ float As[16][68];
    __shared__ float Bs[16][68];
    int tid = threadIdx.x;
    int tx = tid & 15, ty = tid >> 4;
    int mb = blockIdx.x, nb = blockIdx.y;
    float acc[4][4];
#pragma unroll
    for (int u = 0; u < 4; u++)
#pragma unroll
        for (int v = 0; v < 4; v++) acc[u][v] = 0.f;

    int r  = tid >> 2, kq = tid & 3;
    int kb = tid >> 4, n4 = (tid & 15) * 4;
    const float* gx = x + (size_t)(mb * 64 + r) * 2048 + kq * 4;
    const float* gw = wg1 + nb * 64 + n4;

    for (int k0 = 0; k0 < 2048; k0 += 16) {
        fv4 av = *(const fv4*)(gx + k0);
        fv4 bv = *(const fv4*)(gw + (size_t)(k0 + kb) * 256);
        __syncthreads();
#pragma unroll
        for (int u = 0; u < 4; u++) As[kq * 4 + u][r] = av[u];
        *(fv4*)&Bs[kb][n4] = bv;
        __syncthreads();
#pragma unroll
        for (int k = 0; k < 16; k++) {
            fv4 a = *(const fv4*)&As[k][ty * 4];
            fv4 b = *(const fv4*)&Bs[k][tx * 4];
#pragma unroll
            for (int u = 0; u < 4; u++)
#pragma unroll
                for (int v = 0; v < 4; v++) acc[u][v] += a[u] * b[v];
        }
    }
#pragma unroll
    for (int u = 0; u < 4; u++) {
        int row = mb * 64 + ty * 4 + u;
#pragma unroll
        for (int v = 0; v < 4; v++)
            g[(size_t)row * 256 + nb * 64 + tx * 4 + v] = gelu_f(acc[u][v]);
    }
}

// ---------- K2: logits = g @ wg2, softmax, top-2, loss partials ----------
__global__ __launch_bounds__(256) void gate_kernel(
    const float* __restrict__ g, const float* __restrict__ wg2,
    Ctrl* __restrict__ ctrl, int* __restrict__ topidx, float* __restrict__ topval)
{
    __shared__ float wg2s[256 * 9];
    __shared__ float psum_s[8];
    __shared__ float ent_s;
    __shared__ int   cnt_s[8];
    int tid = threadIdx.x;
    for (int i = tid; i < 2048; i += 256) {
        int k = i >> 3, e = i & 7;
        wg2s[k * 9 + e] = wg2[i];
    }
    if (tid < 8) { psum_s[tid] = 0.f; cnt_s[tid] = 0; }
    if (tid == 8) ent_s = 0.f;
    __syncthreads();

    int lane = tid & 63, wv = tid >> 6;
    int t = blockIdx.x * 4 + wv;
    fv4 g4 = *(const fv4*)&g[(size_t)t * 256 + lane * 4];
    float part[8];
#pragma unroll
    for (int e = 0; e < 8; e++) part[e] = 0.f;
#pragma unroll
    for (int u = 0; u < 4; u++) {
        int k = lane * 4 + u;
        float gv = g4[u];
#pragma unroll
        for (int e = 0; e < 8; e++) part[e] += gv * wg2s[k * 9 + e];
    }
#pragma unroll
    for (int e = 0; e < 8; e++)
        for (int off = 32; off; off >>= 1) part[e] += __shfl_xor(part[e], off);

    if (lane == 0) {
        float mx = part[0];
#pragma unroll
        for (int e = 1; e < 8; e++) mx = fmaxf(mx, part[e]);
        float p[8], Z = 0.f;
#pragma unroll
        for (int e = 0; e < 8; e++) { p[e] = expf(part[e] - mx); Z += p[e]; }
        float rz = 1.f / Z;
#pragma unroll
        for (int e = 0; e < 8; e++) p[e] *= rz;
        int i0 = 0;
#pragma unroll
        for (int e = 1; e < 8; e++) if (part[e] > part[i0]) i0 = e;
        int i1 = (i0 == 0) ? 1 : 0;
#pragma unroll
        for (int e = 0; e < 8; e++)
            if (e != i0 && part[e] > part[i1]) i1 = e;
        topidx[2 * t]     = i0;
        topidx[2 * t + 1] = i1;
        topval[2 * t]     = p[i0];
        topval[2 * t + 1] = p[i1];
        float ent = 0.f;
#pragma unroll
        for (int e = 0; e < 8; e++) ent += p[e] * logf(p[e] + 1e-9f);
#pragma unroll
        for (int e = 0; e < 8; e++) atomicAdd(&psum_s[e], p[e]);
        atomicAdd(&ent_s, ent);
        atomicAdd(&cnt_s[i0], 1);
        atomicAdd(&cnt_s[i1], 1);
    }
    __syncthreads();
    if (tid < 8)                    atomicAdd(&ctrl->psum[tid], psum_s[tid]);
    else if (tid == 8)              atomicAdd(&ctrl->entsum, ent_s);
    else if (tid >= 16 && tid < 24) atomicAdd(&ctrl->counts[tid - 16], cnt_s[tid - 16]);
}

// ---------- K4: offsets + tile map (256-granular) + scatter ----------
__global__ __launch_bounds__(256) void route_kernel(
    Ctrl* __restrict__ ctrl, const int* __restrict__ topidx,
    const float* __restrict__ topval, int* __restrict__ rowtok,
    float* __restrict__ rowgate)
{
    __shared__ int cur[8];
    __shared__ int offs_s[8];
    int tid = threadIdx.x;
    if (tid == 0) {
        int off = 0, nt = 0;
        for (int e = 0; e < 8; e++) {
            offs_s[e]    = off;
            ctrl->off[e] = off;
            int c = ctrl->counts[e];
            for (int m = 0; m < c; m += 256) {
                ctrl->tile_e[nt]  = e;
                ctrl->tile_r0[nt] = off + m;
                nt++;
            }
            off += ((c + 255) >> 8) << 8;
        }
        ctrl->ntiles = nt;
    }
    if (tid < 8) cur[tid] = 0;
    __syncthreads();
    for (int t = tid; t < T_TOK; t += 256) {
#pragma unroll
        for (int k = 0; k < 2; k++) {
            int e = topidx[2 * t + k];
            int p = atomicAdd(&cur[e], 1);
            int row = offs_s[e] + p;
            rowtok[row]  = t;
            rowgate[row] = topval[2 * t + k];
        }
    }
}

// ---------- grouped MFMA GEMM: persistent 256 blocks, 256x256 tile, BK=32,
// triple-buffered LDS + raw s_barrier / s_waitcnt vmcnt(4) software pipeline.
// Item list: XCD x <-> tile-group x (4 tiles x 8 nb = 32 items = 32 CUs).
#define WAIT_VM4 0x0F74   // vmcnt(4), lgkm/exp don't-care
#define WAIT_VM0 0x0F70   // vmcnt(0)
template <bool IS_FFN1>
__global__ __launch_bounds__(512, 2) void gemm_grouped(
    const __bf16* __restrict__ A,
    const __bf16* __restrict__ Bt,   // [E][N=2048][K=2048] (B^T)
    const Ctrl* __restrict__ ctrl,
    const int* __restrict__ rowtok,
    const float* __restrict__ rowgate,
    __bf16* __restrict__ hbuf,
    float* __restrict__ y)
{
    const int K = 2048;
    __shared__ __bf16 smem[3 * 16384];   // 3 bufs x (A 8192 + B 8192) bf16 = 96 KB

    int tid  = threadIdx.x;
    int lane = tid & 63, w = tid >> 6;
    int wr = w >> 1, wc = w & 1;
    int c0 = 2 * w, c1 = c0 + 1;
    int sub = lane >> 2;
    int kcg = (lane & 3) ^ ((lane >> 3) & 3);           // XOR bank swizzle (verified R2)
    int frow = (lane & 15) * 32 + (((lane >> 4) ^ ((lane >> 1) & 3)) * 8);

    int ntiles = ctrl->ntiles;
    int x = blockIdx.x & 7, s = blockIdx.x >> 3;        // xcd, cu-slot

    int items[2]; int ni = 0;
    {
        int i0 = x * 32 + s;
        int tl = ((i0 >> 5) << 2) | (i0 & 3);
        if (tl < ntiles) items[ni++] = i0;
    }
    if (s < 8) {
        int i1 = 256 + x * 8 + s;
        int tl = ((i1 >> 5) << 2) | (i1 & 3);
        if (tl < ntiles) items[ni++] = i1;
    }

    for (int it = 0; it < ni; it++) {
        int item = items[it];
        int idx  = item & 31;
        int tl   = ((item >> 5) << 2) | (idx & 3);
        int nb   = (idx >> 2) & 7;
        int e    = ctrl->tile_e[tl];
        int r0   = ctrl->tile_r0[tl];

        // per-item global base pointers (k=0)
        size_t ga0, ga1;
        if constexpr (IS_FFN1) {
            ga0 = (size_t)rowtok[r0 + c0 * 16 + sub] * K;
            ga1 = (size_t)rowtok[r0 + c1 * 16 + sub] * K;
        } else {
            ga0 = (size_t)(r0 + c0 * 16 + sub) * K;
            ga1 = (size_t)(r0 + c1 * 16 + sub) * K;
        }
        const __bf16* pA0 = A + ga0 + kcg * 8;
        const __bf16* pA1 = A + ga1 + kcg * 8;
        const __bf16* pB0 = Bt + ((size_t)e * 2048 + nb * 256 + c0 * 16 + sub) * K + kcg * 8;
        const __bf16* pB1 = Bt + ((size_t)e * 2048 + nb * 256 + c1 * 16 + sub) * K + kcg * 8;

        fv4 acc[4][8];
#pragma unroll
        for (int i = 0; i < 4; i++)
#pragma unroll
            for (int j = 0; j < 8; j++) acc[i][j] = (fv4)0.0f;

        // prologue: all prior-item LDS reads are consumed before this barrier
        __builtin_amdgcn_s_barrier();
#pragma unroll
        for (int pk = 0; pk < 2; pk++) {
            __bf16* lb = smem + pk * 16384;
            g2l16(pA0 + pk * 32, lb + c0 * 512);
            g2l16(pA1 + pk * 32, lb + c1 * 512);
            g2l16(pB0 + pk * 32, lb + 8192 + c0 * 512);
            g2l16(pB1 + pk * 32, lb + 8192 + c1 * 512);
        }

        int bcur = 0;   // LDS buffer byte... element offsets rotate 0,16384,32768
        for (int k = 0; k < 64; k++) {
            if (k < 63) __builtin_amdgcn_s_waitcnt(WAIT_VM4);
            else        __builtin_amdgcn_s_waitcnt(WAIT_VM0);
            __builtin_amdgcn_s_barrier();
            if (k < 62) {
                int bnext = bcur + 32768; if (bnext >= 49152) bnext -= 49152;
                __bf16* lb = smem + bnext;
                int ke = (k + 2) * 32;
                g2l16(pA0 + ke, lb + c0 * 512);
                g2l16(pA1 + ke, lb + c1 * 512);
                g2l16(pB0 + ke, lb + 8192 + c0 * 512);
                g2l16(pB1 + ke, lb + 8192 + c1 * 512);
            }
            const __bf16* lb = smem + bcur;
            bv8 aF[4], bF[8];
#pragma unroll
            for (int i = 0; i < 4; i++)
                aF[i] = *(const bv8*)&lb[(wr * 64 + i * 16) * 32 + frow];
#pragma unroll
            for (int j = 0; j < 8; j++)
                bF[j] = *(const bv8*)&lb[8192 + (wc * 128 + j * 16) * 32 + frow];
#pragma unroll
            for (int i = 0; i < 4; i++)
#pragma unroll
                for (int j = 0; j < 8; j++)
                    acc[i][j] = __builtin_amdgcn_mfma_f32_16x16x32_bf16(aF[i], bF[j], acc[i][j], 0, 0, 0);
            bcur += 16384; if (bcur >= 49152) bcur -= 49152;
        }

        // epilogue: C/D layout col=lane&15, row=(lane>>4)*4+reg
        int colb = nb * 256 + wc * 128 + (lane & 15);
        int rb   = r0 + wr * 64 + (lane >> 4) * 4;
#pragma unroll
        for (int i = 0; i < 4; i++) {
#pragma unroll
            for (int rr = 0; rr < 4; rr++) {
                int rg = rb + i * 16 + rr;
                if constexpr (IS_FFN1) {
                    float gate = rowgate[rg];
                    size_t ho = (size_t)rg * 2048;
#pragma unroll
                    for (int j = 0; j < 8; j++)
                        hbuf[ho + colb + j * 16] = (__bf16)(gelu_f(acc[i][j][rr]) * gate);
                } else {
                    size_t yo = (size_t)rowtok[rg] * 2048;
#pragma unroll
                    for (int j = 0; j < 8; j++)
                        atomicAdd(&y[yo + colb + j * 16], acc[i][j][rr]);
                }
            }
        }
    }
}

// ---------- K5: final loss scalar ----------
__global__ __launch_bounds__(64) void loss_kernel(const Ctrl* __restrict__ ctrl,
                                                  float* __restrict__ out)
{
    if (threadIdx.x == 0) {
        float a = 0.f;
#pragma unroll
        for (int e = 0; e < 8; e++) {
            float pm = ctrl->psum[e] * (1.0f / 4096.0f);
            a += pm * logf(pm + 1e-9f);
        }
        out[0] = a - ctrl->entsum * (1.0f / 4096.0f);
    }
}

extern "C" void kernel_launch(void* const* d_in, const int* in_sizes, int n_in,
                              void* d_out, int out_size, void* d_ws, size_t ws_size,
                              hipStream_t stream)
{
    const float* x   = (const float*)d_in[0];
    const float* wg1 = (const float*)d_in[1];
    const float* wg2 = (const float*)d_in[2];
    const float* w1  = (const float*)d_in[3];
    const float* w2  = (const float*)d_in[4];
    float* out = (float*)d_out;

    char* ws = (char*)d_ws;
    Ctrl*   ctrl    = (Ctrl*)(ws + CTRL_OFF);
    int*    rowtok  = (int*)(ws + ROWTOK_OFF);
    float*  rowgate = (float*)(ws + ROWGATE_OFF);
    int*    topidx  = (int*)(ws + TOPIDX_OFF);
    float*  topval  = (float*)(ws + TOPVAL_OFF);
    float*  g       = (float*)(ws + G_OFF);
    __bf16* xb      = (__bf16*)(ws + XB_OFF);
    __bf16* w1t     = (__bf16*)(ws + W1T_OFF);
    __bf16* w2t     = (__bf16*)(ws + W2T_OFF);
    __bf16* hbuf    = (__bf16*)(ws + HBUF_OFF);

    hipMemsetAsync(ws + CTRL_OFF, 0, 4096, stream);
    hipMemsetAsync(ws + ROWTOK_OFF, 0, 81920, stream);   // rowtok + rowgate
    hipMemsetAsync(d_out, 0, (size_t)out_size * sizeof(float), stream);

    transpose_cvt<<<16384, 256, 0, stream>>>(w1, w2, w1t, w2t);
    cvt_x_kernel<<<8192, 256, 0, stream>>>(x, xb);
    gating_gemm<<<dim3(64, 4), 256, 0, stream>>>(x, wg1, g);
    gate_kernel<<<1024, 256, 0, stream>>>(g, wg2, ctrl, topidx, topval);
    route_kernel<<<1, 256, 0, stream>>>(ctrl, topidx, topval, rowtok, rowgate);
    gemm_grouped<true><<<256, 512, 0, stream>>>(xb, w1t, ctrl, rowtok, rowgate, hbuf, nullptr);
    gemm_grouped<false><<<256, 512, 0, stream>>>(hbuf, w2t, ctrl, rowtok, rowgate, nullptr, out);
    loss_kernel<<<1, 64, 0, stream>>>(ctrl, out + 8388608);
}